// Round 1
// baseline (542.894 us; speedup 1.0000x reference)
//
#include <hip/hip_runtime.h>
#include <stdint.h>

#define NB 1024
#define ND 512
#define NC 100000
#define MT_COUNT 1563          // ceil(100000/64)
#define MARGINF 0.1f

using bf16x8 = __attribute__((ext_vector_type(8))) short;
using f32x4  = __attribute__((ext_vector_type(4))) float;

// ---------- helpers ----------
__device__ __forceinline__ uint32_t f2bf(float f) {
  // round-to-nearest-even fp32 -> bf16 (inputs are finite normals)
  uint32_t u = __float_as_uint(f);
  return (u + 0x7fffu + ((u >> 16) & 1u)) >> 16;
}

// ---------- kernel 1: row-normalize fp32 -> bf16 (one block per row) ----------
__global__ void normalize_rows_kernel(const float* __restrict__ src,
                                      uint16_t* __restrict__ dst) {
  const int row = blockIdx.x;
  const float2* s = (const float2*)(src + (size_t)row * ND);
  float2 v = s[threadIdx.x];               // 256 threads * 2 = 512 elems
  float ss = v.x * v.x + v.y * v.y;
  #pragma unroll
  for (int o = 32; o; o >>= 1) ss += __shfl_down(ss, o);
  __shared__ float red[4];
  if ((threadIdx.x & 63) == 0) red[threadIdx.x >> 6] = ss;
  __syncthreads();
  float tot = red[0] + red[1] + red[2] + red[3];
  float inv = 1.0f / fmaxf(sqrtf(tot), 1e-8f);
  uint32_t lo = f2bf(v.x * inv), hi = f2bf(v.y * inv);
  ((uint32_t*)dst)[(size_t)row * (ND / 2) + threadIdx.x] = lo | (hi << 16);
}

// ---------- kernel 2: exact fp32 target cosine t_b (one block per sample) ----------
__global__ void target_cos_kernel(const float* __restrict__ x,
                                  const float* __restrict__ cls,
                                  const int* __restrict__ tgt,
                                  float* __restrict__ t) {
  const int b = blockIdx.x;
  const int row = tgt[b];
  const float2* xr = (const float2*)(x + (size_t)b * ND);
  const float2* cr = (const float2*)(cls + (size_t)row * ND);
  float2 xv = xr[threadIdx.x], cv = cr[threadIdx.x];
  float sx = xv.x * xv.x + xv.y * xv.y;
  float sc = cv.x * cv.x + cv.y * cv.y;
  float sd = xv.x * cv.x + xv.y * cv.y;
  #pragma unroll
  for (int o = 32; o; o >>= 1) {
    sx += __shfl_down(sx, o);
    sc += __shfl_down(sc, o);
    sd += __shfl_down(sd, o);
  }
  __shared__ float r[3][4];
  const int wv = threadIdx.x >> 6;
  if ((threadIdx.x & 63) == 0) { r[0][wv] = sx; r[1][wv] = sc; r[2][wv] = sd; }
  __syncthreads();
  if (threadIdx.x == 0) {
    float ax = r[0][0] + r[0][1] + r[0][2] + r[0][3];
    float ac = r[1][0] + r[1][1] + r[1][2] + r[1][3];
    float ad = r[2][0] + r[2][1] + r[2][2] + r[2][3];
    t[b] = ad / (fmaxf(sqrtf(ax), 1e-8f) * fmaxf(sqrtf(ac), 1e-8f));
  }
}

// ---------- kernel 3: MFMA GEMM + fused hinge reduction ----------
// Tile: M=64 classes x N=256 inputs, BK=64, 256 threads (4 waves).
// Wave w computes 64(M) x 64(N) at nsub = w*4 .. w*4+3 (4x4 grid of 16x16x32 MFMAs).
// LDS is laid out in MFMA-fragment order: region r (1 KB) holds one 64-lane
// fragment, lane L at base + L*16, so ds_read_b128 is stride-1 (conflict-free)
// and global_load_lds (wave-uniform base + lane*16) can stage it directly.
//   regions 0..7  : A (classes) : r = msub*2 + ki
//   regions 8..39 : B (inputs)  : r = 8 + nsub*2 + ki
__global__ __launch_bounds__(256, 3)
void hinge_gemm_kernel(const uint16_t* __restrict__ Wn,   // [NC][ND] bf16 (normalized)
                       const uint16_t* __restrict__ Xn,   // [NB][ND] bf16 (normalized)
                       const float* __restrict__ t,       // [NB]
                       float* __restrict__ accum) {
  __shared__ __align__(16) uint16_t lds[20480];           // 40 KB
  const int id = blockIdx.x;
  // XCD swizzle: the 4 n-blocks of one m-tile share id%8 (same XCD) for L2 reuse of Wn
  const int mt = (id & 7) + ((id >> 5) << 3);
  const int nt = (id >> 3) & 3;
  if (mt >= MT_COUNT) return;
  const int m0 = mt * 64;
  const int n0 = nt * 256;
  const int lane = threadIdx.x & 63;
  const int wv = threadIdx.x >> 6;
  const int lrow = lane & 15;            // row within a 16-row subtile
  const int lcs = (lane >> 4) << 3;      // col start (bf16) within a 32-wide k-slice

  f32x4 acc[4][4];
  #pragma unroll
  for (int i = 0; i < 4; ++i)
    #pragma unroll
    for (int j = 0; j < 4; ++j)
      acc[i][j] = (f32x4){0.f, 0.f, 0.f, 0.f};

  for (int k0 = 0; k0 < ND; k0 += 64) {
    // ---- stage 40 x 1KB fragment regions, 10 per wave ----
    for (int r = wv; r < 40; r += 4) {
      const int ki = r & 1;
      const uint16_t* gp;
      if (r < 8) {
        int row = m0 + ((r >> 1) << 4) + lrow;
        if (row >= NC) row = NC - 1;     // clamp; masked in epilogue
        gp = Wn + (size_t)row * ND + k0 + ki * 32 + lcs;
      } else {
        const int rb = r - 8;
        const int row = n0 + ((rb >> 1) << 4) + lrow;
        gp = Xn + (size_t)row * ND + k0 + ((rb & 1) * 32) + lcs;
      }
      __builtin_amdgcn_global_load_lds(
          (const __attribute__((address_space(1))) void*)gp,
          (__attribute__((address_space(3))) void*)(lds + r * 512),
          16, 0, 0);
    }
    __syncthreads();
    // ---- compute: 2 k-slices x 4x4 MFMAs ----
    #pragma unroll
    for (int ki = 0; ki < 2; ++ki) {
      bf16x8 af[4], bfr[4];
      #pragma unroll
      for (int ms = 0; ms < 4; ++ms)
        af[ms] = *(const bf16x8*)((const char*)lds + (size_t)(ms * 2 + ki) * 1024 + lane * 16);
      #pragma unroll
      for (int j = 0; j < 4; ++j) {
        const int ns = wv * 4 + j;
        bfr[j] = *(const bf16x8*)((const char*)lds + 8192 + (size_t)(ns * 2 + ki) * 1024 + lane * 16);
      }
      #pragma unroll
      for (int ms = 0; ms < 4; ++ms)
        #pragma unroll
        for (int j = 0; j < 4; ++j)
          acc[ms][j] = __builtin_amdgcn_mfma_f32_16x16x32_bf16(af[ms], bfr[j], acc[ms][j], 0, 0, 0);
    }
    __syncthreads();
  }

  // ---- epilogue: hinge + block reduction ----
  // C/D layout: col(N) = lane&15, row(M) = (lane>>4)*4 + reg
  float local = 0.f;
  const int rbase = (lane >> 4) << 2;
  #pragma unroll
  for (int j = 0; j < 4; ++j) {
    const int n = n0 + (wv * 4 + j) * 16 + (lane & 15);
    const float base = MARGINF - t[n];
    #pragma unroll
    for (int ms = 0; ms < 4; ++ms) {
      const int mr = m0 + ms * 16 + rbase;
      f32x4 v = acc[ms][j];
      #pragma unroll
      for (int rr = 0; rr < 4; ++rr)
        if (mr + rr < NC) local += fmaxf(base + v[rr], 0.f);
    }
  }
  #pragma unroll
  for (int o = 32; o; o >>= 1) local += __shfl_down(local, o);
  __shared__ float part[4];
  if (lane == 0) part[wv] = local;
  __syncthreads();
  if (threadIdx.x == 0)
    atomicAdd(accum, part[0] + part[1] + part[2] + part[3]);
}

// ---------- kernel 4: finalize ----------
__global__ void finalize_kernel(const float* __restrict__ accum, float* __restrict__ out) {
  out[0] = accum[0] * (1.0f / (float)NB) - MARGINF;
}

// ---------- workspace layout ----------
//   Wn   : 0            .. 102,400,000   (NC*ND bf16)
//   Xn   : 102,400,000  .. 103,448,576   (NB*ND bf16)
//   t    : 103,448,576  .. 103,452,672   (NB fp32)
//   acc  : 103,452,672  .. +4
#define WS_WN 0
#define WS_XN 102400000ull
#define WS_T  103448576ull
#define WS_ACC 103452672ull

extern "C" void kernel_launch(void* const* d_in, const int* in_sizes, int n_in,
                              void* d_out, int out_size, void* d_ws, size_t ws_size,
                              hipStream_t stream) {
  const float* inputs = (const float*)d_in[0];
  const float* cls    = (const float*)d_in[1];
  const int*   tgt    = (const int*)d_in[2];
  float* out = (float*)d_out;
  char* ws = (char*)d_ws;
  uint16_t* Wn = (uint16_t*)(ws + WS_WN);
  uint16_t* Xn = (uint16_t*)(ws + WS_XN);
  float* t     = (float*)(ws + WS_T);
  float* accum = (float*)(ws + WS_ACC);

  hipMemsetAsync(accum, 0, sizeof(float), stream);
  normalize_rows_kernel<<<NB, 256, 0, stream>>>(inputs, Xn);
  normalize_rows_kernel<<<NC, 256, 0, stream>>>(cls, Wn);
  target_cos_kernel<<<NB, 256, 0, stream>>>(inputs, cls, tgt, t);
  hinge_gemm_kernel<<<1568 * 4, 256, 0, stream>>>(Wn, Xn, t, accum);
  finalize_kernel<<<1, 1, 0, stream>>>(accum, out);
}

// Round 2
// 540.799 us; speedup vs baseline: 1.0039x; 1.0039x over previous
//
#include <hip/hip_runtime.h>
#include <stdint.h>

#define NB 1024
#define ND 512
#define NC 100000
#define MT2 782          // ceil(NC/128)
#define MARGINF 0.1f

using bf16x8 = __attribute__((ext_vector_type(8))) short;
using f32x4  = __attribute__((ext_vector_type(4))) float;

// ---------- helpers ----------
__device__ __forceinline__ uint32_t f2bf(float f) {
  // round-to-nearest-even fp32 -> bf16
  uint32_t u = __float_as_uint(f);
  return (u + 0x7fffu + ((u >> 16) & 1u)) >> 16;
}

// ---------- kernel 1: row-normalize fp32 -> bf16, ONE WAVE PER ROW ----------
// lane reads 8 consecutive floats (2x float4), butterfly-reduce, one uint4 store.
__global__ __launch_bounds__(256)
void normalize_rows_kernel(const float* __restrict__ src,
                           uint16_t* __restrict__ dst, int nrows) {
  const int lane = threadIdx.x & 63;
  const int wid = (blockIdx.x << 2) + (threadIdx.x >> 6);
  const int nw = gridDim.x << 2;
  for (int row = wid; row < nrows; row += nw) {
    const float4* s = (const float4*)(src + (size_t)row * ND) + (lane << 1);
    float4 a = s[0], b = s[1];
    float ss = a.x*a.x + a.y*a.y + a.z*a.z + a.w*a.w
             + b.x*b.x + b.y*b.y + b.z*b.z + b.w*b.w;
    #pragma unroll
    for (int o = 32; o; o >>= 1) ss += __shfl_xor(ss, o);
    const float inv = 1.0f / fmaxf(sqrtf(ss), 1e-8f);
    uint4 o4;
    o4.x = f2bf(a.x * inv) | (f2bf(a.y * inv) << 16);
    o4.y = f2bf(a.z * inv) | (f2bf(a.w * inv) << 16);
    o4.z = f2bf(b.x * inv) | (f2bf(b.y * inv) << 16);
    o4.w = f2bf(b.z * inv) | (f2bf(b.w * inv) << 16);
    ((uint4*)(dst + (size_t)row * ND))[lane] = o4;
  }
}

// ---------- kernel 2: exact fp32 target cosine t_b (one block per sample) ----------
__global__ void target_cos_kernel(const float* __restrict__ x,
                                  const float* __restrict__ cls,
                                  const int* __restrict__ tgt,
                                  float* __restrict__ t) {
  const int b = blockIdx.x;
  const int row = tgt[b];
  const float2* xr = (const float2*)(x + (size_t)b * ND);
  const float2* cr = (const float2*)(cls + (size_t)row * ND);
  float2 xv = xr[threadIdx.x], cv = cr[threadIdx.x];
  float sx = xv.x * xv.x + xv.y * xv.y;
  float sc = cv.x * cv.x + cv.y * cv.y;
  float sd = xv.x * cv.x + xv.y * cv.y;
  #pragma unroll
  for (int o = 32; o; o >>= 1) {
    sx += __shfl_down(sx, o);
    sc += __shfl_down(sc, o);
    sd += __shfl_down(sd, o);
  }
  __shared__ float r[3][4];
  const int wv = threadIdx.x >> 6;
  if ((threadIdx.x & 63) == 0) { r[0][wv] = sx; r[1][wv] = sc; r[2][wv] = sd; }
  __syncthreads();
  if (threadIdx.x == 0) {
    float ax = r[0][0] + r[0][1] + r[0][2] + r[0][3];
    float ac = r[1][0] + r[1][1] + r[1][2] + r[1][3];
    float ad = r[2][0] + r[2][1] + r[2][2] + r[2][3];
    t[b] = ad / (fmaxf(sqrtf(ax), 1e-8f) * fmaxf(sqrtf(ac), 1e-8f));
  }
}

// ---------- kernel 3: MFMA GEMM + fused hinge reduction ----------
// 512 threads = 8 waves (2 m x 4 n). Block tile M=128(classes) x N=256(inputs),
// BK=64. Wave computes 64x64 via 4x4 of 16x16x32 MFMAs.
// LDS: 48 regions x 1KB, fragment-contiguous (lane L at base+L*16):
//   regions  0..15 : A : r = s*2 + ki   (s = m-subtile 0..7, ki = k-slice)
//   regions 16..47 : B : r = 16 + s*2 + ki (s = n-subtile 0..15)
// Staging base pointers hoisted; K-loop fully unrolled, per-iter VALU = 6 ptr bumps.
__global__ __launch_bounds__(512, 2)
void hinge_gemm_kernel(const uint16_t* __restrict__ Wn,   // [NC][ND] bf16
                       const uint16_t* __restrict__ Xn,   // [NB][ND] bf16
                       const float* __restrict__ t,       // [NB]
                       float* __restrict__ accum) {
  __shared__ __align__(16) uint16_t lds[24576];           // 48 KB
  const int id = blockIdx.x;
  // XCD swizzle: 4 n-tiles of one m-tile share id%8 -> same XCD L2 holds Wn tile
  const int mt = (id & 7) + ((id >> 5) << 3);
  const int nt = (id >> 3) & 3;
  if (mt >= MT2) return;
  const int m0 = mt << 7;
  const int n0 = nt << 8;
  const int lane = threadIdx.x & 63;
  const int wv = threadIdx.x >> 6;       // 0..7
  const int wm = wv & 1;
  const int wn = wv >> 1;                // 0..3
  const int lrow = lane & 15;
  const int lcs = (lane >> 4) << 3;

  // hoist staging addresses: this wave stages regions r = wv + 8*j, j=0..5
  const uint16_t* gp[6];
  #pragma unroll
  for (int j = 0; j < 6; ++j) {
    const int r = wv + (j << 3);
    if (r < 16) {
      int row = m0 + ((r >> 1) << 4) + lrow;
      if (row > NC - 1) row = NC - 1;    // clamp; masked in epilogue
      gp[j] = Wn + (size_t)row * ND + ((r & 1) << 5) + lcs;
    } else {
      const int rb = r - 16;
      const int row = n0 + ((rb >> 1) << 4) + lrow;
      gp[j] = Xn + (size_t)row * ND + ((rb & 1) << 5) + lcs;
    }
  }

  f32x4 acc[4][4];
  #pragma unroll
  for (int i = 0; i < 4; ++i)
    #pragma unroll
    for (int j = 0; j < 4; ++j)
      acc[i][j] = (f32x4){0.f, 0.f, 0.f, 0.f};

  #pragma unroll
  for (int kk = 0; kk < 8; ++kk) {
    #pragma unroll
    for (int j = 0; j < 6; ++j) {
      __builtin_amdgcn_global_load_lds(
          (const __attribute__((address_space(1))) void*)gp[j],
          (__attribute__((address_space(3))) void*)(lds + (wv + (j << 3)) * 512),
          16, 0, 0);
      gp[j] += 64;                       // advance one BK slab (128 B)
    }
    __syncthreads();
    #pragma unroll
    for (int ki = 0; ki < 2; ++ki) {
      bf16x8 af[4], bfr[4];
      #pragma unroll
      for (int ms = 0; ms < 4; ++ms)
        af[ms] = *(const bf16x8*)((const char*)lds +
                 ((((wm << 2) + ms) * 2 + ki) << 10) + (lane << 4));
      #pragma unroll
      for (int j = 0; j < 4; ++j)
        bfr[j] = *(const bf16x8*)((const char*)lds + 16384 +
                 ((((wn << 2) + j) * 2 + ki) << 10) + (lane << 4));
      #pragma unroll
      for (int ms = 0; ms < 4; ++ms)
        #pragma unroll
        for (int j = 0; j < 4; ++j)
          acc[ms][j] = __builtin_amdgcn_mfma_f32_16x16x32_bf16(af[ms], bfr[j], acc[ms][j], 0, 0, 0);
    }
    __syncthreads();
  }

  // ---- epilogue: hinge + block reduction ----
  // C/D layout: col(N) = lane&15, row(M) = (lane>>4)*4 + reg
  float local = 0.f;
  const int rb4 = (lane >> 4) << 2;
  const int mbase = m0 + (wm << 6);
  #pragma unroll
  for (int j = 0; j < 4; ++j) {
    const int n = n0 + (wn << 6) + (j << 4) + (lane & 15);
    const float base = MARGINF - t[n];
    #pragma unroll
    for (int ms = 0; ms < 4; ++ms) {
      const int mr = mbase + (ms << 4) + rb4;
      f32x4 v = acc[ms][j];
      #pragma unroll
      for (int rr = 0; rr < 4; ++rr)
        if (mr + rr < NC) local += fmaxf(base + v[rr], 0.f);
    }
  }
  #pragma unroll
  for (int o = 32; o; o >>= 1) local += __shfl_down(local, o);
  __shared__ float part[8];
  if (lane == 0) part[wv] = local;
  __syncthreads();
  if (threadIdx.x == 0) {
    float s = 0.f;
    #pragma unroll
    for (int i = 0; i < 8; ++i) s += part[i];
    atomicAdd(accum, s);
  }
}

// ---------- kernel 4: finalize ----------
__global__ void finalize_kernel(const float* __restrict__ accum, float* __restrict__ out) {
  out[0] = accum[0] * (1.0f / (float)NB) - MARGINF;
}

// ---------- workspace layout ----------
#define WS_WN 0
#define WS_XN 102400000ull
#define WS_T  103448576ull
#define WS_ACC 103452672ull

extern "C" void kernel_launch(void* const* d_in, const int* in_sizes, int n_in,
                              void* d_out, int out_size, void* d_ws, size_t ws_size,
                              hipStream_t stream) {
  const float* inputs = (const float*)d_in[0];
  const float* cls    = (const float*)d_in[1];
  const int*   tgt    = (const int*)d_in[2];
  float* out = (float*)d_out;
  char* ws = (char*)d_ws;
  uint16_t* Wn = (uint16_t*)(ws + WS_WN);
  uint16_t* Xn = (uint16_t*)(ws + WS_XN);
  float* t     = (float*)(ws + WS_T);
  float* accum = (float*)(ws + WS_ACC);

  hipMemsetAsync(accum, 0, sizeof(float), stream);
  normalize_rows_kernel<<<256, 256, 0, stream>>>(inputs, Xn, NB);
  normalize_rows_kernel<<<4096, 256, 0, stream>>>(cls, Wn, NC);
  target_cos_kernel<<<NB, 256, 0, stream>>>(inputs, cls, tgt, t);
  hinge_gemm_kernel<<<3136, 512, 0, stream>>>(Wn, Xn, t, accum);
  finalize_kernel<<<1, 1, 0, stream>>>(accum, out);
}